// Round 10
// baseline (118.297 us; speedup 1.0000x reference)
//
#include <hip/hip_runtime.h>
#include <hip/hip_bf16.h>

#define NB 20000      // batch
#define KN 16         // neighbors
#define D 256
#define KDIM 512      // 2*D
#define MDIM 512      // 2*OUT stacked
#define CHUNK 16      // dest rows per block
#define LDKC 520      // padded comb LDS row (elems)

typedef __bf16 bf16x8 __attribute__((ext_vector_type(8)));
typedef float f32x4 __attribute__((ext_vector_type(4)));

__device__ inline unsigned short f2bf(float f) {
    union { float f; unsigned int u; } a; a.f = f;
    unsigned int u = a.u;
    unsigned int r = (u + 0x7FFFu + ((u >> 16) & 1u)) >> 16;   // RNE
    return (unsigned short)r;
}

__device__ inline void gload_lds16(const void* g, void* l) {
    __builtin_amdgcn_global_load_lds(
        (const __attribute__((address_space(1))) unsigned int*)g,
        (__attribute__((address_space(3))) unsigned int*)l, 16, 0, 0);
}

// --- kernel 1: W1||W2 f32 -> bf16, stacked [512][512] ---
__global__ __launch_bounds__(256) void convW_kernel(
        const float* __restrict__ W1, const float* __restrict__ W2,
        unsigned short* __restrict__ Wc) {
    int i = blockIdx.x * 256 + threadIdx.x;          // 65536 float4 chunks
    float4 v = (i < 32768) ? reinterpret_cast<const float4*>(W1)[i]
                           : reinterpret_cast<const float4*>(W2)[i - 32768];
    ushort4 o;
    o.x = f2bf(v.x); o.y = f2bf(v.y); o.z = f2bf(v.z); o.w = f2bf(v.w);
    reinterpret_cast<ushort4*>(Wc)[i] = o;
}

// --- fused: block = 16 dest rows. Phase 1: all 4 waves gather (async
//     gload_lds, two 9-row half-stages). Phase 2: all 4 waves GEMM
//     M=128/wave x N=16 x K=512, A from L2-hot Wc, B from LDS comb.
//     comb never goes to global. Block-local sync only. ---
__global__ __launch_bounds__(256, 3) void fused_kernel(
        const int* __restrict__ nodes, const int* __restrict__ neigh,
        const float* __restrict__ feat, const unsigned short* __restrict__ Wc,
        float* __restrict__ out) {
    __shared__ __align__(16) float stage[4][9][D];              // 36864 B
    __shared__ __align__(16) unsigned short combs[CHUNK][LDKC]; // 16640 B

    int tid = threadIdx.x;
    int lane = tid & 63;
    int wid = tid >> 6;
    float* st = &stage[wid][0][0];
    int chunk = blockIdx.x;

    // ================= produce phase: 4 dest rows per wave =================
    int row0 = chunk * CHUNK + wid * 4;
    int node = nodes[row0];
    int idx[KN];
    #pragma unroll
    for (int k = 0; k < KN; k += 4) {
        int4 q = *reinterpret_cast<const int4*>(&neigh[row0 * KN + k]);
        idx[k] = q.x; idx[k + 1] = q.y; idx[k + 2] = q.z; idx[k + 3] = q.w;
    }

    #pragma unroll 1
    for (int r = 0; r < 4; ++r) {
        // ---- half 1: self + n0..7 -> slots 0..8 ----
        asm volatile("s_waitcnt lgkmcnt(0)" ::: "memory");
        gload_lds16(feat + (size_t)node * D + lane * 4, st);
        #pragma unroll
        for (int k = 0; k < 8; ++k)
            gload_lds16(feat + (size_t)idx[k] * D + lane * 4, st + (k + 1) * D);

        // prefetch next row's indices while gathers fly
        int nnode = 0, nidx[KN];
        if (r < 3) {
            int nr = row0 + r + 1;
            nnode = nodes[nr];
            #pragma unroll
            for (int k = 0; k < KN; k += 4) {
                int4 q = *reinterpret_cast<const int4*>(&neigh[nr * KN + k]);
                nidx[k] = q.x; nidx[k + 1] = q.y; nidx[k + 2] = q.z; nidx[k + 3] = q.w;
            }
        }

        asm volatile("s_waitcnt vmcnt(0)" ::: "memory");
        __builtin_amdgcn_sched_barrier(0);
        float4 s = *reinterpret_cast<const float4*>(st + lane * 4);
        float4 m; m.x = 0.f; m.y = 0.f; m.z = 0.f; m.w = 0.f;
        #pragma unroll
        for (int k = 1; k <= 8; ++k) {
            float4 v = *reinterpret_cast<const float4*>(st + k * D + lane * 4);
            m.x += v.x; m.y += v.y; m.z += v.z; m.w += v.w;
        }

        // ---- half 2: n8..15 -> slots 1..8 (reads above retired first) ----
        __builtin_amdgcn_sched_barrier(0);
        asm volatile("s_waitcnt lgkmcnt(0)" ::: "memory");
        #pragma unroll
        for (int k = 8; k < 16; ++k)
            gload_lds16(feat + (size_t)idx[k] * D + lane * 4, st + (k - 7) * D);
        asm volatile("s_waitcnt vmcnt(0)" ::: "memory");
        __builtin_amdgcn_sched_barrier(0);
        #pragma unroll
        for (int k = 1; k <= 8; ++k) {
            float4 v = *reinterpret_cast<const float4*>(st + k * D + lane * 4);
            m.x += v.x; m.y += v.y; m.z += v.z; m.w += v.w;
        }

        const float inv = 1.0f / 16.0f;
        ushort4 sv; sv.x = f2bf(s.x); sv.y = f2bf(s.y);
        sv.z = f2bf(s.z); sv.w = f2bf(s.w);
        ushort4 mv; mv.x = f2bf(m.x * inv); mv.y = f2bf(m.y * inv);
        mv.z = f2bf(m.z * inv); mv.w = f2bf(m.w * inv);
        int dst = wid * 4 + r;
        *reinterpret_cast<ushort4*>(&combs[dst][lane * 4]) = sv;       // self
        *reinterpret_cast<ushort4*>(&combs[dst][D + lane * 4]) = mv;   // mean

        node = nnode;
        #pragma unroll
        for (int k = 0; k < KN; ++k) idx[k] = nidx[k];
    }
    __syncthreads();

    // ================= consume phase: GEMM M=128/wave, N=16 =================
    f32x4 acc[8] = {};
    int rl = lane & 15;
    int kq8 = (lane >> 4) * 8;
    const unsigned short* wbase = Wc + (size_t)(wid * 128 + rl) * KDIM + kq8;

    #pragma unroll 2
    for (int k0 = 0; k0 < KDIM; k0 += 32) {
        bf16x8 bfr = *reinterpret_cast<const bf16x8*>(&combs[rl][k0 + kq8]);
        #pragma unroll
        for (int i = 0; i < 8; ++i) {
            bf16x8 af = *reinterpret_cast<const bf16x8*>(
                wbase + (size_t)i * 16 * KDIM + k0);
            acc[i] = __builtin_amdgcn_mfma_f32_16x16x32_bf16(af, bfr, acc[i], 0, 0, 0);
        }
    }

    // epilogue: C/D layout col=lane&15, row=(lane>>4)*4+reg (verified)
    int col = lane & 15;
    int rq = (lane >> 4) * 4;
    int n = chunk * CHUNK + col;                    // always < NB (1250*16 exact)
    #pragma unroll
    for (int i = 0; i < 8; ++i) {
        int mRow = wid * 128 + i * 16 + rq;
        #pragma unroll
        for (int rr = 0; rr < 4; ++rr) {
            float x = acc[i][rr];
            out[(size_t)(mRow + rr) * NB + n] = x > 0.f ? x : 0.f;
        }
    }
}

extern "C" void kernel_launch(void* const* d_in, const int* in_sizes, int n_in,
                              void* d_out, int out_size, void* d_ws, size_t ws_size,
                              hipStream_t stream) {
    const int*   nodes = (const int*)d_in[0];
    const int*   neigh = (const int*)d_in[1];
    const float* feat  = (const float*)d_in[2];
    const float* W1    = (const float*)d_in[3];
    const float* W2    = (const float*)d_in[4];
    float* out = (float*)d_out;

    unsigned short* Wc = (unsigned short*)d_ws;     // 512KB

    convW_kernel<<<256, 256, 0, stream>>>(W1, W2, Wc);
    fused_kernel<<<NB / CHUNK, 256, 0, stream>>>(nodes, neigh, feat, Wc, out);
}

// Round 11
// 73.163 us; speedup vs baseline: 1.6169x; 1.6169x over previous
//
#include <hip/hip_runtime.h>
#include <hip/hip_bf16.h>

#define NB 20000      // batch
#define KN 16         // neighbors
#define D 256
#define KDIM 512      // 2*D
#define MDIM 512      // 2*OUT stacked
#define NTOT 100000   // feature table rows

typedef __bf16 bf16x8 __attribute__((ext_vector_type(8)));
typedef float f32x4 __attribute__((ext_vector_type(4)));

__device__ inline unsigned short f2bf(float f) {
    union { float f; unsigned int u; } a; a.f = f;
    unsigned int u = a.u;
    unsigned int r = (u + 0x7FFFu + ((u >> 16) & 1u)) >> 16;   // RNE
    return (unsigned short)r;
}

// ---- OCP e4m3fn encode (software, RNE) ----
__device__ inline unsigned int f2fp8(float v) {
    unsigned int s = (__float_as_uint(v) >> 31) << 7;
    float av = fabsf(v);
    if (av >= 448.f) return s | 0x7Eu;               // saturate to ±448
    if (av < 0.015625f) {                             // subnormal: m*2^-9
        unsigned int m = (unsigned int)rintf(av * 512.f);
        return s | m;                                 // m==8 -> min normal, still valid
    }
    int ex; float fr = frexpf(av, &ex);               // av = fr*2^ex, fr in [0.5,1)
    int m = (int)rintf(fr * 16.f - 8.f);              // 0..8
    int e = ex - 1;                                   // -6..8
    if (m == 8) { m = 0; e += 1; }
    if (e > 8) return s | 0x7Eu;
    return s | (unsigned int)((e + 7) << 3) | (unsigned int)m;
}

#if __has_builtin(__builtin_amdgcn_cvt_f32_fp8)
#define FP8_DEC(d, i) __builtin_amdgcn_cvt_f32_fp8((d), (i))
#else
__device__ inline float fp8_sw_dec(unsigned int d, int i) {
    unsigned int b = (d >> (i * 8)) & 0xFFu;
    unsigned int s = b >> 7, ef = (b >> 3) & 15u, m = b & 7u;
    float v = (ef == 0) ? (float)m * 0.001953125f
                        : __uint_as_float(((ef + 120u) << 23) | (m << 20));
    return s ? -v : v;
}
#define FP8_DEC(d, i) fp8_sw_dec((d), (i))
#endif

// --- kernel 1: W1||W2 f32 -> bf16, stacked [512][512] ---
__global__ __launch_bounds__(256) void convW_kernel(
        const float* __restrict__ W1, const float* __restrict__ W2,
        unsigned short* __restrict__ Wc) {
    int i = blockIdx.x * 256 + threadIdx.x;          // 65536 float4 chunks
    float4 v = (i < 32768) ? reinterpret_cast<const float4*>(W1)[i]
                           : reinterpret_cast<const float4*>(W2)[i - 32768];
    ushort4 o;
    o.x = f2bf(v.x); o.y = f2bf(v.y); o.z = f2bf(v.z); o.w = f2bf(v.w);
    reinterpret_cast<ushort4*>(Wc)[i] = o;
}

// --- kernel 2: feature table f32 -> fp8 e4m3 (streaming 102->26MB) ---
__global__ __launch_bounds__(256) void conv_fp8_kernel(
        const float* __restrict__ feat, unsigned int* __restrict__ tab) {
    const long long total = (long long)NTOT * D / 4;  // 6.4M dwords
    long long i = (long long)blockIdx.x * 256 + threadIdx.x;
    const long long stride = (long long)gridDim.x * 256;
    for (; i < total; i += stride) {
        float4 v = reinterpret_cast<const float4*>(feat)[i];
        unsigned int u = f2fp8(v.x) | (f2fp8(v.y) << 8)
                       | (f2fp8(v.z) << 16) | (f2fp8(v.w) << 24);
        tab[i] = u;
    }
}

// --- kernel 3: gather: self from f32 table, neighbors from fp8 table ---
__global__ __launch_bounds__(256) void agg_fp8_kernel(
        const int* __restrict__ nodes, const int* __restrict__ neigh,
        const float* __restrict__ feat, const unsigned int* __restrict__ tab,
        unsigned short* __restrict__ comb) {
    int w = threadIdx.x >> 6;
    int lane = threadIdx.x & 63;
    int b = blockIdx.x * 4 + w;                      // grid = 5000 -> b < 20000
    const float4* f4 = reinterpret_cast<const float4*>(feat);  // row = 64 float4

    int node = nodes[b];
    float4 s = f4[(size_t)node * 64 + lane];         // self: 16B/lane f32

    float m0 = 0.f, m1 = 0.f, m2 = 0.f, m3 = 0.f;
    #pragma unroll
    for (int k = 0; k < KN; ++k) {
        int idx = neigh[b * KN + k];
        unsigned int d = tab[(size_t)idx * 64 + lane];   // 4B/lane = 4 fp8
        m0 += FP8_DEC(d, 0); m1 += FP8_DEC(d, 1);
        m2 += FP8_DEC(d, 2); m3 += FP8_DEC(d, 3);
    }
    const float inv = 1.0f / 16.0f;

    ushort4 sv; sv.x = f2bf(s.x); sv.y = f2bf(s.y); sv.z = f2bf(s.z); sv.w = f2bf(s.w);
    ushort4 mv; mv.x = f2bf(m0 * inv); mv.y = f2bf(m1 * inv);
    mv.z = f2bf(m2 * inv); mv.w = f2bf(m3 * inv);

    unsigned short* row = comb + (size_t)b * KDIM;
    *reinterpret_cast<ushort4*>(row + lane * 4) = sv;          // self  [0,256)
    *reinterpret_cast<ushort4*>(row + D + lane * 4) = mv;      // mean  [256,512)
}

// --- kernel 4: GEMM BM=256 x BN=80, BK=32, LDK=40; grid (250,2)=500 blocks
//     (balanced ~2/CU); comb re-read x2 instead of x4. R2 inner structure. ---
#define G4M 256
#define G4N 80
#define LDK 40

__global__ __launch_bounds__(256) void gemm4_kernel(
        const unsigned short* __restrict__ Wc,    // [512][512] bf16
        const unsigned short* __restrict__ Cb,    // [20000][512] bf16
        float* __restrict__ out) {                // [512][20000] f32
    __shared__ __align__(16) unsigned short As[G4M * LDK];   // 20.5KB
    __shared__ __align__(16) unsigned short Bs[G4N * LDK];   // 6.4KB

    int tid = threadIdx.x;
    int lane = tid & 63;
    int wid = tid >> 6;                 // 0..3 -> m-slice of 64
    int mBase = blockIdx.y * G4M;
    int nBase = blockIdx.x * G4N;       // exact fit: 250*80 = 20000

    f32x4 acc[4][5] = {};

    int srow = tid >> 2;                // 0..63
    int scol = (tid & 3) * 8;           // 0,8,16,24
    int rl = lane & 15;
    int kq = (lane >> 4) * 8;

    for (int k0 = 0; k0 < KDIM; k0 += 32) {
        // stage A: 256 rows x 32 elems; 4 chunks/thread
        #pragma unroll
        for (int h = 0; h < 4; ++h) {
            int r = srow + h * 64;
            uint4 va = *reinterpret_cast<const uint4*>(
                Wc + (size_t)(mBase + r) * KDIM + k0 + scol);
            *reinterpret_cast<uint4*>(&As[r * LDK + scol]) = va;
        }
        // stage B: 80 rows x 32 elems = 320 chunks; 256 + 64
        {
            int r = srow;               // rows 0..63
            uint4 vb = *reinterpret_cast<const uint4*>(
                Cb + (size_t)(nBase + r) * KDIM + k0 + scol);
            *reinterpret_cast<uint4*>(&Bs[r * LDK + scol]) = vb;
            if (tid < 64) {
                int r2 = 64 + (tid >> 2);
                int sc2 = (tid & 3) * 8;
                uint4 v2 = *reinterpret_cast<const uint4*>(
                    Cb + (size_t)(nBase + r2) * KDIM + k0 + sc2);
                *reinterpret_cast<uint4*>(&Bs[r2 * LDK + sc2]) = v2;
            }
        }
        __syncthreads();

        bf16x8 af[4], bfr[5];
        #pragma unroll
        for (int i = 0; i < 4; ++i)
            af[i] = *reinterpret_cast<const bf16x8*>(
                &As[(wid * 64 + i * 16 + rl) * LDK + kq]);
        #pragma unroll
        for (int j = 0; j < 5; ++j)
            bfr[j] = *reinterpret_cast<const bf16x8*>(
                &Bs[(j * 16 + rl) * LDK + kq]);
        #pragma unroll
        for (int i = 0; i < 4; ++i)
            #pragma unroll
            for (int j = 0; j < 5; ++j)
                acc[i][j] = __builtin_amdgcn_mfma_f32_16x16x32_bf16(
                    af[i], bfr[j], acc[i][j], 0, 0, 0);
        __syncthreads();
    }

    // epilogue: C/D layout col=lane&15, row=(lane>>4)*4+reg (verified)
    int col = lane & 15;
    int rq = (lane >> 4) * 4;
    #pragma unroll
    for (int i = 0; i < 4; ++i) {
        int mRow = mBase + wid * 64 + i * 16 + rq;
        #pragma unroll
        for (int j = 0; j < 5; ++j) {
            int n = nBase + j * 16 + col;             // always < NB
            #pragma unroll
            for (int rr = 0; rr < 4; ++rr) {
                float x = acc[i][j][rr];
                out[(size_t)(mRow + rr) * NB + n] = x > 0.f ? x : 0.f;
            }
        }
    }
}

extern "C" void kernel_launch(void* const* d_in, const int* in_sizes, int n_in,
                              void* d_out, int out_size, void* d_ws, size_t ws_size,
                              hipStream_t stream) {
    const int*   nodes = (const int*)d_in[0];
    const int*   neigh = (const int*)d_in[1];
    const float* feat  = (const float*)d_in[2];
    const float* W1    = (const float*)d_in[3];
    const float* W2    = (const float*)d_in[4];
    float* out = (float*)d_out;

    // ws layout: Wc (512KB) | fp8 table (25.6MB) | comb (20.48MB)
    const size_t WC_BYTES  = (size_t)MDIM * KDIM * 2;        // 524288
    const size_t TAB_BYTES = (size_t)NTOT * D;               // 25600000
    unsigned short* Wc   = (unsigned short*)d_ws;
    unsigned int*   tab  = (unsigned int*)((char*)d_ws + WC_BYTES);
    unsigned short* comb = (unsigned short*)((char*)d_ws + WC_BYTES + TAB_BYTES);

    convW_kernel<<<256, 256, 0, stream>>>(W1, W2, Wc);
    conv_fp8_kernel<<<2048, 256, 0, stream>>>(feat, tab);
    agg_fp8_kernel<<<NB / 4, 256, 0, stream>>>(nodes, neigh, feat, tab, comb);
    gemm4_kernel<<<dim3(NB / G4N, MDIM / G4M), 256, 0, stream>>>(Wc, comb, out);
}

// Round 12
// 70.971 us; speedup vs baseline: 1.6668x; 1.0309x over previous
//
#include <hip/hip_runtime.h>
#include <hip/hip_bf16.h>

#define NB 20000      // batch
#define KN 16         // neighbors
#define D 256
#define KDIM 512      // 2*D
#define MDIM 512      // 2*OUT stacked
#define NTOT 100000   // feature table rows

typedef __bf16 bf16x8 __attribute__((ext_vector_type(8)));
typedef float f32x4 __attribute__((ext_vector_type(4)));

__device__ inline unsigned short f2bf(float f) {
    union { float f; unsigned int u; } a; a.f = f;
    unsigned int u = a.u;
    unsigned int r = (u + 0x7FFFu + ((u >> 16) & 1u)) >> 16;   // RNE
    return (unsigned short)r;
}

// ---- OCP e4m3fn encode (software fallback, RNE) ----
__device__ inline unsigned int f2fp8(float v) {
    unsigned int s = (__float_as_uint(v) >> 31) << 7;
    float av = fabsf(v);
    if (av >= 448.f) return s | 0x7Eu;               // saturate to ±448
    if (av < 0.015625f) {                             // subnormal: m*2^-9
        unsigned int m = (unsigned int)rintf(av * 512.f);
        return s | m;
    }
    int ex; float fr = frexpf(av, &ex);               // av = fr*2^ex, fr in [0.5,1)
    int m = (int)rintf(fr * 16.f - 8.f);              // 0..8
    int e = ex - 1;
    if (m == 8) { m = 0; e += 1; }
    if (e > 8) return s | 0x7Eu;
    return s | (unsigned int)((e + 7) << 3) | (unsigned int)m;
}

#if __has_builtin(__builtin_amdgcn_cvt_f32_fp8)
#define FP8_DEC(d, i) __builtin_amdgcn_cvt_f32_fp8((d), (i))
#else
__device__ inline float fp8_sw_dec(unsigned int d, int i) {
    unsigned int b = (d >> (i * 8)) & 0xFFu;
    unsigned int s = b >> 7, ef = (b >> 3) & 15u, m = b & 7u;
    float v = (ef == 0) ? (float)m * 0.001953125f
                        : __uint_as_float(((ef + 120u) << 23) | (m << 20));
    return s ? -v : v;
}
#define FP8_DEC(d, i) fp8_sw_dec((d), (i))
#endif

// --- kernel 1: W1||W2 f32 -> bf16, stacked [512][512] ---
__global__ __launch_bounds__(256) void convW_kernel(
        const float* __restrict__ W1, const float* __restrict__ W2,
        unsigned short* __restrict__ Wc) {
    int i = blockIdx.x * 256 + threadIdx.x;          // 65536 float4 chunks
    float4 v = (i < 32768) ? reinterpret_cast<const float4*>(W1)[i]
                           : reinterpret_cast<const float4*>(W2)[i - 32768];
    ushort4 o;
    o.x = f2bf(v.x); o.y = f2bf(v.y); o.z = f2bf(v.z); o.w = f2bf(v.w);
    reinterpret_cast<ushort4*>(Wc)[i] = o;
}

// --- kernel 2: feature table f32 -> fp8 e4m3 (streaming; HW cvt if avail) ---
__global__ __launch_bounds__(256) void conv_fp8_kernel(
        const float* __restrict__ feat, unsigned int* __restrict__ tab) {
    const long long total = (long long)NTOT * D / 4;  // 6.4M dwords
    long long i = (long long)blockIdx.x * 256 + threadIdx.x;
    const long long stride = (long long)gridDim.x * 256;
    for (; i < total; i += stride) {
        float4 v = reinterpret_cast<const float4*>(feat)[i];
#if __has_builtin(__builtin_amdgcn_cvt_pk_fp8_f32)
        int u = __builtin_amdgcn_cvt_pk_fp8_f32(v.x, v.y, 0, 0);   // low word
        u = __builtin_amdgcn_cvt_pk_fp8_f32(v.z, v.w, u, 1);       // high word
        tab[i] = (unsigned int)u;
#else
        tab[i] = f2fp8(v.x) | (f2fp8(v.y) << 8)
               | (f2fp8(v.z) << 16) | (f2fp8(v.w) << 24);
#endif
    }
}

// --- kernel 3: gather: self from f32 table, neighbors from fp8 table ---
__global__ __launch_bounds__(256) void agg_fp8_kernel(
        const int* __restrict__ nodes, const int* __restrict__ neigh,
        const float* __restrict__ feat, const unsigned int* __restrict__ tab,
        unsigned short* __restrict__ comb) {
    int w = threadIdx.x >> 6;
    int lane = threadIdx.x & 63;
    int b = blockIdx.x * 4 + w;                      // grid = 5000 -> b < 20000
    const float4* f4 = reinterpret_cast<const float4*>(feat);  // row = 64 float4

    int node = nodes[b];
    float4 s = f4[(size_t)node * 64 + lane];         // self: 16B/lane f32

    float m0 = 0.f, m1 = 0.f, m2 = 0.f, m3 = 0.f;
    #pragma unroll
    for (int k = 0; k < KN; ++k) {
        int idx = neigh[b * KN + k];
        unsigned int d = tab[(size_t)idx * 64 + lane];   // 4B/lane = 4 fp8
        m0 += FP8_DEC(d, 0); m1 += FP8_DEC(d, 1);
        m2 += FP8_DEC(d, 2); m3 += FP8_DEC(d, 3);
    }
    const float inv = 1.0f / 16.0f;

    ushort4 sv; sv.x = f2bf(s.x); sv.y = f2bf(s.y); sv.z = f2bf(s.z); sv.w = f2bf(s.w);
    ushort4 mv; mv.x = f2bf(m0 * inv); mv.y = f2bf(m1 * inv);
    mv.z = f2bf(m2 * inv); mv.w = f2bf(m3 * inv);

    unsigned short* row = comb + (size_t)b * KDIM;
    *reinterpret_cast<ushort4*>(row + lane * 4) = sv;          // self  [0,256)
    *reinterpret_cast<ushort4*>(row + D + lane * 4) = mv;      // mean  [256,512)
}

// --- kernel 4: GEMM BM=256 x BN=80, BK=32, LDK=40; 1D grid of 500 with
//     bijective XCD swizzle so the 2 m-blocks sharing comb rows land on the
//     SAME XCD (comb re-read becomes an L2 hit). R2-proven inner structure. ---
#define G4M 256
#define G4N 80
#define LDK 40
#define G4BLK 500     // (NB/G4N) * (MDIM/G4M) = 250*2

__global__ __launch_bounds__(256) void gemm4_kernel(
        const unsigned short* __restrict__ Wc,    // [512][512] bf16
        const unsigned short* __restrict__ Cb,    // [20000][512] bf16
        float* __restrict__ out) {                // [512][20000] f32
    __shared__ __align__(16) unsigned short As[G4M * LDK];   // 20.5KB
    __shared__ __align__(16) unsigned short Bs[G4N * LDK];   // 6.4KB

    // bijective XCD swizzle (m204): physical b -> logical pair-id
    int b = blockIdx.x;
    const int q = G4BLK / 8, r = G4BLK % 8;       // 62, 4
    int xcd = b & 7, slot = b >> 3;
    int logical = (xcd < r) ? xcd * (q + 1) + slot
                            : r * (q + 1) + (xcd - r) * q + slot;
    int ntile = logical >> 1;                     // 0..249
    int mtile = logical & 1;                      // 0..1

    int tid = threadIdx.x;
    int lane = tid & 63;
    int wid = tid >> 6;                 // 0..3 -> m-slice of 64
    int mBase = mtile * G4M;
    int nBase = ntile * G4N;            // exact fit: 250*80 = 20000

    f32x4 acc[4][5] = {};

    int srow = tid >> 2;                // 0..63
    int scol = (tid & 3) * 8;           // 0,8,16,24
    int rl = lane & 15;
    int kq = (lane >> 4) * 8;

    for (int k0 = 0; k0 < KDIM; k0 += 32) {
        // stage A: 256 rows x 32 elems; 4 chunks/thread
        #pragma unroll
        for (int h = 0; h < 4; ++h) {
            int rr = srow + h * 64;
            uint4 va = *reinterpret_cast<const uint4*>(
                Wc + (size_t)(mBase + rr) * KDIM + k0 + scol);
            *reinterpret_cast<uint4*>(&As[rr * LDK + scol]) = va;
        }
        // stage B: 80 rows x 32 elems = 320 chunks; 256 + 64
        {
            int rr = srow;              // rows 0..63
            uint4 vb = *reinterpret_cast<const uint4*>(
                Cb + (size_t)(nBase + rr) * KDIM + k0 + scol);
            *reinterpret_cast<uint4*>(&Bs[rr * LDK + scol]) = vb;
            if (tid < 64) {
                int r2 = 64 + (tid >> 2);
                int sc2 = (tid & 3) * 8;
                uint4 v2 = *reinterpret_cast<const uint4*>(
                    Cb + (size_t)(nBase + r2) * KDIM + k0 + sc2);
                *reinterpret_cast<uint4*>(&Bs[r2 * LDK + sc2]) = v2;
            }
        }
        __syncthreads();

        bf16x8 af[4], bfr[5];
        #pragma unroll
        for (int i = 0; i < 4; ++i)
            af[i] = *reinterpret_cast<const bf16x8*>(
                &As[(wid * 64 + i * 16 + rl) * LDK + kq]);
        #pragma unroll
        for (int j = 0; j < 5; ++j)
            bfr[j] = *reinterpret_cast<const bf16x8*>(
                &Bs[(j * 16 + rl) * LDK + kq]);
        #pragma unroll
        for (int i = 0; i < 4; ++i)
            #pragma unroll
            for (int j = 0; j < 5; ++j)
                acc[i][j] = __builtin_amdgcn_mfma_f32_16x16x32_bf16(
                    af[i], bfr[j], acc[i][j], 0, 0, 0);
        __syncthreads();
    }

    // epilogue: C/D layout col=lane&15, row=(lane>>4)*4+reg (verified)
    int col = lane & 15;
    int rq = (lane >> 4) * 4;
    #pragma unroll
    for (int i = 0; i < 4; ++i) {
        int mRow = mBase + wid * 64 + i * 16 + rq;
        #pragma unroll
        for (int j = 0; j < 5; ++j) {
            int n = nBase + j * 16 + col;             // always < NB
            #pragma unroll
            for (int rr = 0; rr < 4; ++rr) {
                float x = acc[i][j][rr];
                out[(size_t)(mRow + rr) * NB + n] = x > 0.f ? x : 0.f;
            }
        }
    }
}

extern "C" void kernel_launch(void* const* d_in, const int* in_sizes, int n_in,
                              void* d_out, int out_size, void* d_ws, size_t ws_size,
                              hipStream_t stream) {
    const int*   nodes = (const int*)d_in[0];
    const int*   neigh = (const int*)d_in[1];
    const float* feat  = (const float*)d_in[2];
    const float* W1    = (const float*)d_in[3];
    const float* W2    = (const float*)d_in[4];
    float* out = (float*)d_out;

    // ws layout: Wc (512KB) | fp8 table (25.6MB) | comb (20.48MB)
    const size_t WC_BYTES  = (size_t)MDIM * KDIM * 2;        // 524288
    const size_t TAB_BYTES = (size_t)NTOT * D;               // 25600000
    unsigned short* Wc   = (unsigned short*)d_ws;
    unsigned int*   tab  = (unsigned int*)((char*)d_ws + WC_BYTES);
    unsigned short* comb = (unsigned short*)((char*)d_ws + WC_BYTES + TAB_BYTES);

    convW_kernel<<<256, 256, 0, stream>>>(W1, W2, Wc);
    conv_fp8_kernel<<<2048, 256, 0, stream>>>(feat, tab);
    agg_fp8_kernel<<<NB / 4, 256, 0, stream>>>(nodes, neigh, feat, tab, comb);
    gemm4_kernel<<<G4BLK, 256, 0, stream>>>(Wc, comb, out);
}

// Round 13
// 66.742 us; speedup vs baseline: 1.7725x; 1.0634x over previous
//
#include <hip/hip_runtime.h>
#include <hip/hip_bf16.h>

#define NB 20000      // batch
#define KN 16         // neighbors
#define D 256
#define KDIM 512      // 2*D
#define MDIM 512      // 2*OUT stacked
#define NTOT 100000   // feature table rows

// prep kernel block-role ranges
#define PB_W    256                    // convW blocks
#define PB_CONV 1600                   // fp8-table conversion blocks
#define PB_SELF 1250                   // self-gather blocks (16 rows each)
#define PB_TOT  (PB_W + PB_CONV + PB_SELF)

typedef __bf16 bf16x8 __attribute__((ext_vector_type(8)));
typedef float f32x4 __attribute__((ext_vector_type(4)));

__device__ inline unsigned short f2bf(float f) {
    union { float f; unsigned int u; } a; a.f = f;
    unsigned int u = a.u;
    unsigned int r = (u + 0x7FFFu + ((u >> 16) & 1u)) >> 16;   // RNE
    return (unsigned short)r;
}

// ---- OCP e4m3fn encode (software fallback, RNE) ----
__device__ inline unsigned int f2fp8(float v) {
    unsigned int s = (__float_as_uint(v) >> 31) << 7;
    float av = fabsf(v);
    if (av >= 448.f) return s | 0x7Eu;
    if (av < 0.015625f) {
        unsigned int m = (unsigned int)rintf(av * 512.f);
        return s | m;
    }
    int ex; float fr = frexpf(av, &ex);
    int m = (int)rintf(fr * 16.f - 8.f);
    int e = ex - 1;
    if (m == 8) { m = 0; e += 1; }
    if (e > 8) return s | 0x7Eu;
    return s | (unsigned int)((e + 7) << 3) | (unsigned int)m;
}

#if __has_builtin(__builtin_amdgcn_cvt_f32_fp8)
#define FP8_DEC(d, i) __builtin_amdgcn_cvt_f32_fp8((d), (i))
#else
__device__ inline float fp8_sw_dec(unsigned int d, int i) {
    unsigned int b = (d >> (i * 8)) & 0xFFu;
    unsigned int s = b >> 7, ef = (b >> 3) & 15u, m = b & 7u;
    float v = (ef == 0) ? (float)m * 0.001953125f
                        : __uint_as_float(((ef + 120u) << 23) | (m << 20));
    return s ? -v : v;
}
#define FP8_DEC(d, i) fp8_sw_dec((d), (i))
#endif

// --- prep kernel: 3 block-role ranges.
//     [0,256):        W1||W2 f32 -> bf16 Wc[512][512]
//     [256,1856):     feat f32 -> fp8 table (grid-stride streaming)
//     [1856,3106):    self-row gather: comb[b][0:256] = bf16(feat[nodes[b]])
//     Streaming (HBM path) and random self-gather (L3 path) overlap. ---
__global__ __launch_bounds__(256) void prep_kernel(
        const float* __restrict__ W1, const float* __restrict__ W2,
        const float* __restrict__ feat, const int* __restrict__ nodes,
        unsigned short* __restrict__ Wc, unsigned int* __restrict__ tab,
        unsigned short* __restrict__ comb) {
    int blk = blockIdx.x;
    int tid = threadIdx.x;

    if (blk < PB_W) {
        int i = blk * 256 + tid;                     // 65536 float4 chunks
        float4 v = (i < 32768) ? reinterpret_cast<const float4*>(W1)[i]
                               : reinterpret_cast<const float4*>(W2)[i - 32768];
        ushort4 o;
        o.x = f2bf(v.x); o.y = f2bf(v.y); o.z = f2bf(v.z); o.w = f2bf(v.w);
        reinterpret_cast<ushort4*>(Wc)[i] = o;
    } else if (blk < PB_W + PB_CONV) {
        const long long total = (long long)NTOT * D / 4;   // 6.4M dwords
        long long i = (long long)(blk - PB_W) * 256 + tid;
        const long long stride = (long long)PB_CONV * 256;
        for (; i < total; i += stride) {
            float4 v = reinterpret_cast<const float4*>(feat)[i];
#if __has_builtin(__builtin_amdgcn_cvt_pk_fp8_f32)
            int u = __builtin_amdgcn_cvt_pk_fp8_f32(v.x, v.y, 0, 0);
            u = __builtin_amdgcn_cvt_pk_fp8_f32(v.z, v.w, u, 1);
            tab[i] = (unsigned int)u;
#else
            tab[i] = f2fp8(v.x) | (f2fp8(v.y) << 8)
                   | (f2fp8(v.z) << 16) | (f2fp8(v.w) << 24);
#endif
        }
    } else {
        // self gather: 16 rows per block, 4 per wave
        int base = (blk - PB_W - PB_CONV) * 16;
        int lane = tid & 63;
        int wid = tid >> 6;
        const float4* f4 = reinterpret_cast<const float4*>(feat);
        #pragma unroll
        for (int r = 0; r < 4; ++r) {
            int b = base + wid * 4 + r;
            int node = nodes[b];
            float4 s = f4[(size_t)node * 64 + lane];
            ushort4 sv; sv.x = f2bf(s.x); sv.y = f2bf(s.y);
            sv.z = f2bf(s.z); sv.w = f2bf(s.w);
            *reinterpret_cast<ushort4*>(comb + (size_t)b * KDIM + lane * 4) = sv;
        }
    }
}

// --- agg_n: neighbor-only gather from fp8 table -> mean half of comb ---
__global__ __launch_bounds__(256) void agg_n_kernel(
        const int* __restrict__ neigh, const unsigned int* __restrict__ tab,
        unsigned short* __restrict__ comb) {
    int w = threadIdx.x >> 6;
    int lane = threadIdx.x & 63;
    int b = blockIdx.x * 4 + w;                      // grid = 5000
    int nb = b * KN;

    float m0 = 0.f, m1 = 0.f, m2 = 0.f, m3 = 0.f;
    #pragma unroll
    for (int k = 0; k < KN; ++k) {
        int idx = neigh[nb + k];
        unsigned int d = tab[(size_t)idx * 64 + lane];   // 4B/lane = 4 fp8
        m0 += FP8_DEC(d, 0); m1 += FP8_DEC(d, 1);
        m2 += FP8_DEC(d, 2); m3 += FP8_DEC(d, 3);
    }
    const float inv = 1.0f / 16.0f;
    ushort4 mv; mv.x = f2bf(m0 * inv); mv.y = f2bf(m1 * inv);
    mv.z = f2bf(m2 * inv); mv.w = f2bf(m3 * inv);
    *reinterpret_cast<ushort4*>(comb + (size_t)b * KDIM + D + lane * 4) = mv;
}

// --- gemm4: BM=256 x BN=80, BK=32, LDK=40; bijective XCD swizzle pairs the
//     two m-blocks sharing comb rows onto the same XCD. (R12-proven) ---
#define G4M 256
#define G4N 80
#define LDK 40
#define G4BLK 500     // (NB/G4N) * (MDIM/G4M)

__global__ __launch_bounds__(256) void gemm4_kernel(
        const unsigned short* __restrict__ Wc,    // [512][512] bf16
        const unsigned short* __restrict__ Cb,    // [20000][512] bf16
        float* __restrict__ out) {                // [512][20000] f32
    __shared__ __align__(16) unsigned short As[G4M * LDK];   // 20.5KB
    __shared__ __align__(16) unsigned short Bs[G4N * LDK];   // 6.4KB

    int b = blockIdx.x;
    const int q = G4BLK / 8, r = G4BLK % 8;       // 62, 4
    int xcd = b & 7, slot = b >> 3;
    int logical = (xcd < r) ? xcd * (q + 1) + slot
                            : r * (q + 1) + (xcd - r) * q + slot;
    int ntile = logical >> 1;                     // 0..249
    int mtile = logical & 1;                      // 0..1

    int tid = threadIdx.x;
    int lane = tid & 63;
    int wid = tid >> 6;
    int mBase = mtile * G4M;
    int nBase = ntile * G4N;

    f32x4 acc[4][5] = {};

    int srow = tid >> 2;
    int scol = (tid & 3) * 8;
    int rl = lane & 15;
    int kq = (lane >> 4) * 8;

    for (int k0 = 0; k0 < KDIM; k0 += 32) {
        #pragma unroll
        for (int h = 0; h < 4; ++h) {
            int rr = srow + h * 64;
            uint4 va = *reinterpret_cast<const uint4*>(
                Wc + (size_t)(mBase + rr) * KDIM + k0 + scol);
            *reinterpret_cast<uint4*>(&As[rr * LDK + scol]) = va;
        }
        {
            int rr = srow;
            uint4 vb = *reinterpret_cast<const uint4*>(
                Cb + (size_t)(nBase + rr) * KDIM + k0 + scol);
            *reinterpret_cast<uint4*>(&Bs[rr * LDK + scol]) = vb;
            if (tid < 64) {
                int r2 = 64 + (tid >> 2);
                int sc2 = (tid & 3) * 8;
                uint4 v2 = *reinterpret_cast<const uint4*>(
                    Cb + (size_t)(nBase + r2) * KDIM + k0 + sc2);
                *reinterpret_cast<uint4*>(&Bs[r2 * LDK + sc2]) = v2;
            }
        }
        __syncthreads();

        bf16x8 af[4], bfr[5];
        #pragma unroll
        for (int i = 0; i < 4; ++i)
            af[i] = *reinterpret_cast<const bf16x8*>(
                &As[(wid * 64 + i * 16 + rl) * LDK + kq]);
        #pragma unroll
        for (int j = 0; j < 5; ++j)
            bfr[j] = *reinterpret_cast<const bf16x8*>(
                &Bs[(j * 16 + rl) * LDK + kq]);
        #pragma unroll
        for (int i = 0; i < 4; ++i)
            #pragma unroll
            for (int j = 0; j < 5; ++j)
                acc[i][j] = __builtin_amdgcn_mfma_f32_16x16x32_bf16(
                    af[i], bfr[j], acc[i][j], 0, 0, 0);
        __syncthreads();
    }

    int col = lane & 15;
    int rq = (lane >> 4) * 4;
    #pragma unroll
    for (int i = 0; i < 4; ++i) {
        int mRow = mBase + wid * 64 + i * 16 + rq;
        #pragma unroll
        for (int j = 0; j < 5; ++j) {
            int n = nBase + j * 16 + col;
            #pragma unroll
            for (int rr = 0; rr < 4; ++rr) {
                float x = acc[i][j][rr];
                out[(size_t)(mRow + rr) * NB + n] = x > 0.f ? x : 0.f;
            }
        }
    }
}

extern "C" void kernel_launch(void* const* d_in, const int* in_sizes, int n_in,
                              void* d_out, int out_size, void* d_ws, size_t ws_size,
                              hipStream_t stream) {
    const int*   nodes = (const int*)d_in[0];
    const int*   neigh = (const int*)d_in[1];
    const float* feat  = (const float*)d_in[2];
    const float* W1    = (const float*)d_in[3];
    const float* W2    = (const float*)d_in[4];
    float* out = (float*)d_out;

    // ws layout: Wc (512KB) | fp8 table (25.6MB) | comb (20.48MB)
    const size_t WC_BYTES  = (size_t)MDIM * KDIM * 2;
    const size_t TAB_BYTES = (size_t)NTOT * D;
    unsigned short* Wc   = (unsigned short*)d_ws;
    unsigned int*   tab  = (unsigned int*)((char*)d_ws + WC_BYTES);
    unsigned short* comb = (unsigned short*)((char*)d_ws + WC_BYTES + TAB_BYTES);

    prep_kernel<<<PB_TOT, 256, 0, stream>>>(W1, W2, feat, nodes, Wc, tab, comb);
    agg_n_kernel<<<NB / 4, 256, 0, stream>>>(neigh, tab, comb);
    gemm4_kernel<<<G4BLK, 256, 0, stream>>>(Wc, comb, out);
}

// Round 14
// 66.572 us; speedup vs baseline: 1.7770x; 1.0025x over previous
//
#include <hip/hip_runtime.h>
#include <hip/hip_bf16.h>

#define NB 20000      // batch
#define KN 16         // neighbors
#define D 256
#define KDIM 512      // 2*D
#define MDIM 512      // 2*OUT stacked
#define NTOT 100000   // feature table rows

// prep kernel block-role ranges
#define PB_W    256                    // convW blocks
#define PB_CONV 1600                   // fp8-table conversion blocks
#define PB_SELF 1250                   // self-gather blocks (16 rows each)
#define PB_TOT  (PB_W + PB_CONV + PB_SELF)

typedef __bf16 bf16x8 __attribute__((ext_vector_type(8)));
typedef float f32x4 __attribute__((ext_vector_type(4)));

__device__ inline unsigned short f2bf(float f) {
    union { float f; unsigned int u; } a; a.f = f;
    unsigned int u = a.u;
    unsigned int r = (u + 0x7FFFu + ((u >> 16) & 1u)) >> 16;   // RNE
    return (unsigned short)r;
}

// ---- OCP e4m3fn encode (software fallback, RNE) ----
__device__ inline unsigned int f2fp8(float v) {
    unsigned int s = (__float_as_uint(v) >> 31) << 7;
    float av = fabsf(v);
    if (av >= 448.f) return s | 0x7Eu;
    if (av < 0.015625f) {
        unsigned int m = (unsigned int)rintf(av * 512.f);
        return s | m;
    }
    int ex; float fr = frexpf(av, &ex);
    int m = (int)rintf(fr * 16.f - 8.f);
    int e = ex - 1;
    if (m == 8) { m = 0; e += 1; }
    if (e > 8) return s | 0x7Eu;
    return s | (unsigned int)((e + 7) << 3) | (unsigned int)m;
}

#if __has_builtin(__builtin_amdgcn_cvt_f32_fp8)
#define FP8_DEC(d, i) __builtin_amdgcn_cvt_f32_fp8((d), (i))
#else
__device__ inline float fp8_sw_dec(unsigned int d, int i) {
    unsigned int b = (d >> (i * 8)) & 0xFFu;
    unsigned int s = b >> 7, ef = (b >> 3) & 15u, m = b & 7u;
    float v = (ef == 0) ? (float)m * 0.001953125f
                        : __uint_as_float(((ef + 120u) << 23) | (m << 20));
    return s ? -v : v;
}
#define FP8_DEC(d, i) fp8_sw_dec((d), (i))
#endif

// --- prep kernel: 3 block-role ranges (R13-proven).
//     [0,256):        W1||W2 f32 -> bf16 Wc[512][512]
//     [256,1856):     feat f32 -> fp8 table (grid-stride streaming)
//     [1856,3106):    self-row gather: comb[b][0:256] = bf16(feat[nodes[b]]) ---
__global__ __launch_bounds__(256) void prep_kernel(
        const float* __restrict__ W1, const float* __restrict__ W2,
        const float* __restrict__ feat, const int* __restrict__ nodes,
        unsigned short* __restrict__ Wc, unsigned int* __restrict__ tab,
        unsigned short* __restrict__ comb) {
    int blk = blockIdx.x;
    int tid = threadIdx.x;

    if (blk < PB_W) {
        int i = blk * 256 + tid;                     // 65536 float4 chunks
        float4 v = (i < 32768) ? reinterpret_cast<const float4*>(W1)[i]
                               : reinterpret_cast<const float4*>(W2)[i - 32768];
        ushort4 o;
        o.x = f2bf(v.x); o.y = f2bf(v.y); o.z = f2bf(v.z); o.w = f2bf(v.w);
        reinterpret_cast<ushort4*>(Wc)[i] = o;
    } else if (blk < PB_W + PB_CONV) {
        const long long total = (long long)NTOT * D / 4;   // 6.4M dwords
        long long i = (long long)(blk - PB_W) * 256 + tid;
        const long long stride = (long long)PB_CONV * 256;
        for (; i < total; i += stride) {
            float4 v = reinterpret_cast<const float4*>(feat)[i];
#if __has_builtin(__builtin_amdgcn_cvt_pk_fp8_f32)
            int u = __builtin_amdgcn_cvt_pk_fp8_f32(v.x, v.y, 0, 0);
            u = __builtin_amdgcn_cvt_pk_fp8_f32(v.z, v.w, u, 1);
            tab[i] = (unsigned int)u;
#else
            tab[i] = f2fp8(v.x) | (f2fp8(v.y) << 8)
                   | (f2fp8(v.z) << 16) | (f2fp8(v.w) << 24);
#endif
        }
    } else {
        int base = (blk - PB_W - PB_CONV) * 16;
        int lane = tid & 63;
        int wid = tid >> 6;
        const float4* f4 = reinterpret_cast<const float4*>(feat);
        #pragma unroll
        for (int r = 0; r < 4; ++r) {
            int b = base + wid * 4 + r;
            int node = nodes[b];
            float4 s = f4[(size_t)node * 64 + lane];
            ushort4 sv; sv.x = f2bf(s.x); sv.y = f2bf(s.y);
            sv.z = f2bf(s.z); sv.w = f2bf(s.w);
            *reinterpret_cast<ushort4*>(comb + (size_t)b * KDIM + lane * 4) = sv;
        }
    }
}

// --- agg_n: neighbor-only gather from fp8 table -> mean half of comb ---
__global__ __launch_bounds__(256) void agg_n_kernel(
        const int* __restrict__ neigh, const unsigned int* __restrict__ tab,
        unsigned short* __restrict__ comb) {
    int w = threadIdx.x >> 6;
    int lane = threadIdx.x & 63;
    int b = blockIdx.x * 4 + w;                      // grid = 5000
    int nb = b * KN;

    float m0 = 0.f, m1 = 0.f, m2 = 0.f, m3 = 0.f;
    #pragma unroll
    for (int k = 0; k < KN; ++k) {
        int idx = neigh[nb + k];
        unsigned int d = tab[(size_t)idx * 64 + lane];   // 4B/lane = 4 fp8
        m0 += FP8_DEC(d, 0); m1 += FP8_DEC(d, 1);
        m2 += FP8_DEC(d, 2); m3 += FP8_DEC(d, 3);
    }
    const float inv = 1.0f / 16.0f;
    ushort4 mv; mv.x = f2bf(m0 * inv); mv.y = f2bf(m1 * inv);
    mv.z = f2bf(m2 * inv); mv.w = f2bf(m3 * inv);
    *reinterpret_cast<ushort4*>(comb + (size_t)b * KDIM + D + lane * 4) = mv;
}

// --- gemm5: BM=256 x BN=80, BK=64 (16 barriers instead of 32), LDK=72 pad;
//     bijective XCD swizzle pairs m-blocks sharing comb rows on one XCD;
//     non-temporal epilogue stores keep comb/Wc resident in L2. ---
#define G4M 256
#define G4N 80
#define GBK2 64
#define LDK2 72
#define G4BLK 500     // (NB/G4N) * (MDIM/G4M)

__global__ __launch_bounds__(256) void gemm5_kernel(
        const unsigned short* __restrict__ Wc,    // [512][512] bf16
        const unsigned short* __restrict__ Cb,    // [20000][512] bf16
        float* __restrict__ out) {                // [512][20000] f32
    __shared__ __align__(16) unsigned short As[G4M * LDK2];   // 36.9KB
    __shared__ __align__(16) unsigned short Bs[G4N * LDK2];   // 11.5KB

    int b = blockIdx.x;
    const int q = G4BLK / 8, r = G4BLK % 8;       // 62, 4
    int xcd = b & 7, slot = b >> 3;
    int logical = (xcd < r) ? xcd * (q + 1) + slot
                            : r * (q + 1) + (xcd - r) * q + slot;
    int ntile = logical >> 1;                     // 0..249
    int mtile = logical & 1;                      // 0..1

    int tid = threadIdx.x;
    int lane = tid & 63;
    int wid = tid >> 6;                 // 0..3 -> m-slice of 64
    int mBase = mtile * G4M;
    int nBase = ntile * G4N;            // exact fit: 250*80 = 20000

    f32x4 acc[4][5] = {};

    int srow8 = tid >> 3;               // 0..31
    int scol8 = (tid & 7) * 8;          // 0..56 elems within 64
    int rl = lane & 15;
    int kq = (lane >> 4) * 8;

    for (int k0 = 0; k0 < KDIM; k0 += GBK2) {
        // stage A: 256 rows x 64 elems = 2048 16B-chunks; 8 per thread
        #pragma unroll
        for (int h = 0; h < 8; ++h) {
            int rr = srow8 + h * 32;
            uint4 va = *reinterpret_cast<const uint4*>(
                Wc + (size_t)(mBase + rr) * KDIM + k0 + scol8);
            *reinterpret_cast<uint4*>(&As[rr * LDK2 + scol8]) = va;
        }
        // stage B: 80 rows x 8 chunks = 640 chunks; 256+256+128
        {
            int c = tid;                            // 0..255
            int rr = c >> 3, ch = (c & 7) * 8;
            uint4 vb = *reinterpret_cast<const uint4*>(
                Cb + (size_t)(nBase + rr) * KDIM + k0 + ch);
            *reinterpret_cast<uint4*>(&Bs[rr * LDK2 + ch]) = vb;
            int c1 = tid + 256;
            int r1 = c1 >> 3, ch1 = (c1 & 7) * 8;
            uint4 v1 = *reinterpret_cast<const uint4*>(
                Cb + (size_t)(nBase + r1) * KDIM + k0 + ch1);
            *reinterpret_cast<uint4*>(&Bs[r1 * LDK2 + ch1]) = v1;
            if (tid < 128) {
                int c2 = tid + 512;
                int r2 = c2 >> 3, ch2 = (c2 & 7) * 8;
                uint4 v2 = *reinterpret_cast<const uint4*>(
                    Cb + (size_t)(nBase + r2) * KDIM + k0 + ch2);
                *reinterpret_cast<uint4*>(&Bs[r2 * LDK2 + ch2]) = v2;
            }
        }
        __syncthreads();

        #pragma unroll
        for (int kk = 0; kk < GBK2; kk += 32) {
            bf16x8 af[4], bfr[5];
            #pragma unroll
            for (int i = 0; i < 4; ++i)
                af[i] = *reinterpret_cast<const bf16x8*>(
                    &As[(wid * 64 + i * 16 + rl) * LDK2 + kk + kq]);
            #pragma unroll
            for (int j = 0; j < 5; ++j)
                bfr[j] = *reinterpret_cast<const bf16x8*>(
                    &Bs[(j * 16 + rl) * LDK2 + kk + kq]);
            #pragma unroll
            for (int i = 0; i < 4; ++i)
                #pragma unroll
                for (int j = 0; j < 5; ++j)
                    acc[i][j] = __builtin_amdgcn_mfma_f32_16x16x32_bf16(
                        af[i], bfr[j], acc[i][j], 0, 0, 0);
        }
        __syncthreads();
    }

    // epilogue: C/D layout col=lane&15, row=(lane>>4)*4+reg (verified);
    // non-temporal stores to avoid evicting comb/Wc from L2
    int col = lane & 15;
    int rq = (lane >> 4) * 4;
    #pragma unroll
    for (int i = 0; i < 4; ++i) {
        int mRow = mBase + wid * 64 + i * 16 + rq;
        #pragma unroll
        for (int j = 0; j < 5; ++j) {
            int n = nBase + j * 16 + col;             // always < NB
            #pragma unroll
            for (int rr = 0; rr < 4; ++rr) {
                float x = acc[i][j][rr];
                x = x > 0.f ? x : 0.f;
                __builtin_nontemporal_store(x, &out[(size_t)(mRow + rr) * NB + n]);
            }
        }
    }
}

extern "C" void kernel_launch(void* const* d_in, const int* in_sizes, int n_in,
                              void* d_out, int out_size, void* d_ws, size_t ws_size,
                              hipStream_t stream) {
    const int*   nodes = (const int*)d_in[0];
    const int*   neigh = (const int*)d_in[1];
    const float* feat  = (const float*)d_in[2];
    const float* W1    = (const float*)d_in[3];
    const float* W2    = (const float*)d_in[4];
    float* out = (float*)d_out;

    // ws layout: Wc (512KB) | fp8 table (25.6MB) | comb (20.48MB)
    const size_t WC_BYTES  = (size_t)MDIM * KDIM * 2;
    const size_t TAB_BYTES = (size_t)NTOT * D;
    unsigned short* Wc   = (unsigned short*)d_ws;
    unsigned int*   tab  = (unsigned int*)((char*)d_ws + WC_BYTES);
    unsigned short* comb = (unsigned short*)((char*)d_ws + WC_BYTES + TAB_BYTES);

    prep_kernel<<<PB_TOT, 256, 0, stream>>>(W1, W2, feat, nodes, Wc, tab, comb);
    agg_n_kernel<<<NB / 4, 256, 0, stream>>>(neigh, tab, comb);
    gemm5_kernel<<<G4BLK, 256, 0, stream>>>(Wc, comb, out);
}